// Round 8
// baseline (592.551 us; speedup 1.0000x reference)
//
#include <hip/hip_runtime.h>
#include <hip/hip_bf16.h>

typedef __hip_bfloat16 bf16;
typedef float f32x4 __attribute__((ext_vector_type(4)));
typedef short bf16x8 __attribute__((ext_vector_type(8)));

#define HW 65536
#define NB 8

__device__ __forceinline__ bf16 f2b(float v){ return __float2bfloat16(v); }
__device__ __forceinline__ float b2f(bf16 v){ return __bfloat162float(v); }
__device__ __forceinline__ short fbits(float v){ bf16 b = f2b(v); return *(short*)&b; }

// conv3 B-pack: unit = ((br*2+half)*9 + ks)*6 + nc ; k_local = (lane>>4)*8+j -> c = half*32+k_local, tap = ks
__global__ void pack_w3(const float* __restrict__ wx, const float* __restrict__ wg,
                        short* __restrict__ dst)
{
    int idx = blockIdx.x * 256 + threadIdx.x;
    if (idx >= 110592) return;
    int unit = idx >> 9, r = idx & 511;
    int lane = r >> 3, j = r & 7;
    int nc = unit % 6; int u2 = unit / 6;
    int ks = u2 % 9;  int u3 = u2 / 9;
    int half = u3 & 1, br = u3 >> 1;
    int n = nc * 16 + (lane & 15);
    int c = half * 32 + ((lane >> 4) << 3) + j;
    const float* w = br ? wg : wx;
    dst[idx] = fbits((n < 81) ? w[n * 576 + c * 9 + ks] : 0.f);
}

// conv2 B-pack: unit = ((br*2+half)*5 + ks2)*2 + nc ; k = ks2*32+(lane>>4)*8+j -> tap=k>>4, c16=k&15
__global__ void pack_w2(const float* __restrict__ wx, const float* __restrict__ wg,
                        short* __restrict__ dst)
{
    int idx = blockIdx.x * 256 + threadIdx.x;
    if (idx >= 20480) return;
    int unit = idx >> 9, r = idx & 511;
    int lane = r >> 3, j = r & 7;
    int nc = unit & 1; int u2 = unit >> 1;
    int ks2 = u2 % 5; int u3 = u2 / 5;
    int half = u3 & 1, br = u3 >> 1;
    int n = half * 32 + nc * 16 + (lane & 15);
    int k = ks2 * 32 + ((lane >> 4) << 3) + j;
    int tap = k >> 4, c16 = k & 15;
    const float* w = br ? wg : wx;
    dst[idx] = fbits((tap < 9) ? w[n * 144 + c16 * 9 + tap] : 0.f);
}

__global__ void s_kernel(const float* __restrict__ out0, const float* __restrict__ d,
                         float* __restrict__ s)
{
    int i = blockIdx.x * 256 + threadIdx.x;
    s[i] = out0[i] - d[i];
}

// One dyn-filter branch per block: 16x16 output tile.
// conv1 (VALU) -> h1 ch-last -> [conv2 half-h MFMA -> conv3 half-h MFMA] x2
// -> register softmax + 9x9 filter. g-branch also writes d to out2.
__global__ __launch_bounds__(256, 3) void branch_kernel(
    const float* __restrict__ origin, const float* __restrict__ residual,
    const float* __restrict__ fxw1, const float* __restrict__ fxb1,
    const float* __restrict__ fxb2, const float* __restrict__ fxb3,
    const float* __restrict__ fgw1, const float* __restrict__ fgb1,
    const float* __restrict__ fgb2, const float* __restrict__ fgb3,
    const short* __restrict__ Bp2, const short* __restrict__ Bp3,
    bf16* __restrict__ pack, float* __restrict__ dout)
{
    __shared__ float s_src[576];       // 24x24 f32
    __shared__ bf16  s_h1[6720];       // [21 rows x 20][16ch], row 20 zero (K-pad)
    __shared__ bf16  s_h2[12960];      // [324][40] ch-last padded (32 used)

    const int t = threadIdx.x;
    const int lane = t & 63;
    const int w = t >> 6;
    const int g = lane >> 4;
    const int j16 = lane & 15;
    const int tile = blockIdx.x;
    const int br = blockIdx.y >> 3;
    const int img = blockIdx.y & 7;
    const int y0 = (tile >> 4) << 4, x0 = (tile & 15) << 4;
    const long ib = (long)img * HW;

    const float* w1 = br ? fgw1 : fxw1;
    const float* b1 = br ? fgb1 : fxb1;
    const float* b2 = br ? fgb2 : fxb2;
    const float* b3 = br ? fgb3 : fxb3;

    // ---- phase 1: stage src; g-branch also materializes d into out2 ----
    for (int idx = t; idx < 576; idx += 256) {
        int sy = idx / 24, sx = idx - sy * 24;
        int gy = y0 - 4 + sy, gx = x0 - 4 + sx;
        float v = 0.f;
        if ((unsigned)gy < 256u && (unsigned)gx < 256u) {
            long o = ib + (gy << 8) + gx;
            if (br) {
                v = origin[o] - residual[o];
                dout[o] = v;                    // idempotent overlap writes
            } else {
                v = residual[o];
            }
        }
        s_src[idx] = v;
    }
    __syncthreads();

    // ---- phase 2: conv1 (1->16) VALU -> h1 bf16 ch-last; zero K-pad row ----
    for (int p = t; p < 400; p += 256) {
        int py = p / 20, px = p - py * 20;
        int gy = y0 - 2 + py, gx = x0 - 2 + px;
        bool in = (unsigned)gy < 256u && (unsigned)gx < 256u;
        float sw[9];
        #pragma unroll
        for (int dy = 0; dy < 3; dy++)
            #pragma unroll
            for (int dx = 0; dx < 3; dx++)
                sw[dy * 3 + dx] = s_src[(py + 1 + dy) * 24 + px + 1 + dx];
        #pragma unroll
        for (int c = 0; c < 16; c++) {
            float a = b1[c];
            const float* wc = w1 + c * 9;
            #pragma unroll
            for (int q = 0; q < 9; q++) a = fmaf(wc[q], sw[q], a);
            s_h1[p * 16 + c] = f2b(in ? fmaxf(a, 0.f) : 0.f);
        }
    }
    for (int idx = t; idx < 320; idx += 256) s_h1[6400 + idx] = f2b(0.f);

    // ---- logits acc: 96 = 6 ncols x (4 rows/lane), persists across halves ----
    f32x4 acc[4][6];
    #pragma unroll
    for (int mr = 0; mr < 4; mr++)
        #pragma unroll
        for (int nc = 0; nc < 6; nc++) {
            int n = nc * 16 + j16;
            float bb = (n < 81) ? b3[n] : -1e30f;
            acc[mr][nc] = (f32x4){bb, bb, bb, bb};
        }
    __syncthreads();

    // ---- phases 3/4 per 32-channel half ----
    for (int h = 0; h < 2; h++) {
        // conv2 (16->64) MFMA: produce out-channels [h*32, h*32+32)
        {
            const short* Bw2 = Bp2 + (br * 2 + h) * 5120;
            bf16x8 B2[5][2];
            #pragma unroll
            for (int ks = 0; ks < 5; ks++)
                #pragma unroll
                for (int nc = 0; nc < 2; nc++)
                    B2[ks][nc] = *(const bf16x8*)(Bw2 + ((ks * 2 + nc) << 9) + lane * 8);
            const int kgh = g >> 1, c0 = (g & 1) * 8;
            for (int mrow = w; mrow < 21; mrow += 4) {
                int pA = mrow * 16 + j16;
                int pyA = pA / 18, pxA = pA - pyA * 18;
                f32x4 acc2[2];
                #pragma unroll
                for (int nc = 0; nc < 2; nc++) {
                    float bb = b2[h * 32 + nc * 16 + j16];
                    acc2[nc] = (f32x4){bb, bb, bb, bb};
                }
                #pragma unroll
                for (int ks = 0; ks < 5; ks++) {
                    int tap = 2 * ks + kgh;
                    int ty = (tap * 11) >> 5;
                    int tx = tap - ty * 3;
                    int pl = (pyA + ty) * 20 + pxA + tx;
                    if (pl > 419) pl = 419;          // pad-tap garbage row, B=0
                    bf16x8 A = *(const bf16x8*)&s_h1[pl * 16 + c0];
                    #pragma unroll
                    for (int nc = 0; nc < 2; nc++)
                        acc2[nc] = __builtin_amdgcn_mfma_f32_16x16x32_bf16(A, B2[ks][nc], acc2[nc], 0, 0, 0);
                }
                #pragma unroll
                for (int nc = 0; nc < 2; nc++) {
                    int ch = nc * 16 + j16;
                    #pragma unroll
                    for (int r = 0; r < 4; r++) {
                        int p = mrow * 16 + g * 4 + r;
                        if (p < 324)
                            s_h2[p * 40 + ch] = f2b(fmaxf(acc2[nc][r], 0.f));
                    }
                }
            }
        }
        __syncthreads();

        // conv3 (64->81) MFMA: accumulate K-slice c in [h*32, h*32+32)
        {
            const short* Bw3 = Bp3 + (br * 2 + h) * 27648;
            for (int ks = 0; ks < 9; ks++) {
                bf16x8 B3[6];
                #pragma unroll
                for (int nc = 0; nc < 6; nc++)
                    B3[nc] = *(const bf16x8*)(Bw3 + ((ks * 6 + nc) << 9) + lane * 8);
                int dy = (ks * 11) >> 5;
                int dx = ks - dy * 3;
                #pragma unroll
                for (int mr = 0; mr < 4; mr++) {
                    int mrow = w * 4 + mr;
                    int pl = (mrow + dy) * 18 + j16 + dx;
                    bf16x8 A = *(const bf16x8*)&s_h2[pl * 40 + g * 8];
                    #pragma unroll
                    for (int nc = 0; nc < 6; nc++)
                        acc[mr][nc] = __builtin_amdgcn_mfma_f32_16x16x32_bf16(A, B3[nc], acc[mr][nc], 0, 0, 0);
                }
            }
        }
        __syncthreads();
    }

    // ---- phase 5: register softmax (16 lanes x 6 ncols) + 9x9 filter ----
    int ti[6], tj[6];
    #pragma unroll
    for (int nc = 0; nc < 6; nc++) {
        int n = nc * 16 + j16;
        int tt = n / 9;
        ti[nc] = tt; tj[nc] = n - tt * 9;
    }
    #pragma unroll
    for (int mr = 0; mr < 4; mr++) {
        int mrow = w * 4 + mr;
        bf16 res[4];
        #pragma unroll
        for (int r = 0; r < 4; r++) {
            float mx = -1e30f;
            #pragma unroll
            for (int nc = 0; nc < 6; nc++) mx = fmaxf(mx, acc[mr][nc][r]);
            #pragma unroll
            for (int msk = 1; msk < 16; msk <<= 1) mx = fmaxf(mx, __shfl_xor(mx, msk));
            float ssum = 0.f, fsum = 0.f;
            int px = g * 4 + r;
            #pragma unroll
            for (int nc = 0; nc < 6; nc++) {
                float e = __expf(acc[mr][nc][r] - mx);   // pads: exp(-1e30) = 0
                ssum += e;
                int idx = (mrow + ti[nc]) * 24 + px + tj[nc];
                fsum += e * s_src[idx > 575 ? 575 : idx];
            }
            #pragma unroll
            for (int msk = 1; msk < 16; msk <<= 1) {
                ssum += __shfl_xor(ssum, msk);
                fsum += __shfl_xor(fsum, msk);
            }
            res[r] = f2b(fsum / ssum);
        }
        if (j16 == 0) {
            long base = ((long)(img * 2 + br) << 16) + ((y0 + mrow) << 8) + x0 + g * 4;
            pack[base + 0] = res[0];
            pack[base + 1] = res[1];
            pack[base + 2] = res[2];
            pack[base + 3] = res[3];
        }
    }
}

// c1(2->64)+c2(64->1) fused per tile, 2 barriers total; out0 = s + d
__global__ __launch_bounds__(256) void tail_kernel(
    const bf16* __restrict__ pack,
    const float* __restrict__ c1w, const float* __restrict__ c1b,
    const float* __restrict__ c2w, const float* __restrict__ c2b,
    const float* __restrict__ d2, float* __restrict__ out0)
{
    __shared__ float s_x[400], s_g[400];   // 20x20
    __shared__ bf16  s_h[22680];           // [324][70] (64 used; 70 => 2-way banks)

    const int t = threadIdx.x;
    const int tile = blockIdx.x;
    const int img = blockIdx.y;
    const int y0 = (tile >> 4) << 4, x0 = (tile & 15) << 4;

    for (int idx = t; idx < 400; idx += 256) {
        int hy = idx / 20, hx = idx - hy * 20;
        int gy = y0 - 2 + hy, gx = x0 - 2 + hx;
        float vx = 0.f, vg = 0.f;
        if ((unsigned)gy < 256u && (unsigned)gx < 256u) {
            int o = (gy << 8) + gx;
            vx = b2f(pack[((img * 2 + 0) << 16) + o]);
            vg = b2f(pack[((img * 2 + 1) << 16) + o]);
        }
        s_x[idx] = vx;
        s_g[idx] = vg;
    }
    __syncthreads();

    // produce: c1 for all 64 channels of each pixel
    for (int p = t; p < 324; p += 256) {
        int hy = p / 18, hx = p - hy * 18;
        int gy = y0 - 1 + hy, gx = x0 - 1 + hx;
        bool in = (unsigned)gy < 256u && (unsigned)gx < 256u;
        float sx[9], sg[9];
        #pragma unroll
        for (int dy = 0; dy < 3; dy++)
            #pragma unroll
            for (int dx = 0; dx < 3; dx++) {
                sx[dy * 3 + dx] = s_x[(hy + dy) * 20 + hx + dx];
                sg[dy * 3 + dx] = s_g[(hy + dy) * 20 + hx + dx];
            }
        for (int c = 0; c < 64; c++) {
            float a = c1b[c];
            const float* wp = c1w + c * 18;
            #pragma unroll
            for (int q = 0; q < 9; q++) {
                a = fmaf(wp[q], sx[q], a);
                a = fmaf(wp[9 + q], sg[q], a);
            }
            s_h[p * 70 + c] = f2b(in ? fmaxf(a, 0.f) : 0.f);
        }
    }
    __syncthreads();

    // consume: c2 (64ch x 9 taps) via u32 pair reads + bf16 bit-unpack
    const int ly = t >> 4, lx = t & 15;
    float sacc = c2b[0];
    #pragma unroll
    for (int t9 = 0; t9 < 9; t9++) {
        int pl = (ly + t9 / 3) * 18 + lx + (t9 % 3);
        const bf16* rowp = s_h + pl * 70;
        #pragma unroll
        for (int c = 0; c < 64; c += 2) {
            unsigned int u = *(const unsigned int*)&rowp[c];
            float flo = __uint_as_float(u << 16);
            float fhi = __uint_as_float(u & 0xffff0000u);
            sacc = fmaf(c2w[c * 9 + t9],       flo, sacc);
            sacc = fmaf(c2w[(c + 1) * 9 + t9], fhi, sacc);
        }
    }
    long o = (long)img * HW + ((y0 + ly) << 8) + (x0 + lx);
    out0[o] = sacc + d2[o];
}

extern "C" void kernel_launch(void* const* d_in, const int* in_sizes, int n_in,
                              void* d_out, int out_size, void* d_ws, size_t ws_size,
                              hipStream_t stream)
{
    const float* origin   = (const float*)d_in[0];
    const float* residual = (const float*)d_in[1];
    const float* fxw1 = (const float*)d_in[2];  const float* fxb1 = (const float*)d_in[3];
    const float* fxw2 = (const float*)d_in[4];  const float* fxb2 = (const float*)d_in[5];
    const float* fxw3 = (const float*)d_in[6];  const float* fxb3 = (const float*)d_in[7];
    const float* fgw1 = (const float*)d_in[8];  const float* fgb1 = (const float*)d_in[9];
    const float* fgw2 = (const float*)d_in[10]; const float* fgb2 = (const float*)d_in[11];
    const float* fgw3 = (const float*)d_in[12]; const float* fgb3 = (const float*)d_in[13];
    const float* c1w  = (const float*)d_in[14]; const float* c1b  = (const float*)d_in[15];
    const float* c2w  = (const float*)d_in[16]; const float* c2b  = (const float*)d_in[17];

    float* out0 = (float*)d_out;                 // out = s + d
    float* out1 = out0 + (long)NB * HW;          // s (temp: packed bf16 x_/g_)
    float* out2 = out1 + (long)NB * HW;          // d
    bf16*  pack = (bf16*)out1;

    short* Bp2 = (short*)d_ws;                   // 20480 shorts
    short* Bp3 = Bp2 + 20480;                    // 110592 shorts

    pack_w2<<<80, 256, 0, stream>>>(fxw2, fgw2, Bp2);
    pack_w3<<<432, 256, 0, stream>>>(fxw3, fgw3, Bp3);

    branch_kernel<<<dim3(256, 16), 256, 0, stream>>>(
        origin, residual,
        fxw1, fxb1, fxb2, fxb3,
        fgw1, fgb1, fgb2, fgb3,
        Bp2, Bp3, pack, out2);

    tail_kernel<<<dim3(256, 8), 256, 0, stream>>>(pack, c1w, c1b, c2w, c2b, out2, out0);

    s_kernel<<<(NB * HW) / 256, 256, 0, stream>>>(out0, out2, out1);
}

// Round 9
// 507.005 us; speedup vs baseline: 1.1687x; 1.1687x over previous
//
#include <hip/hip_runtime.h>
#include <hip/hip_bf16.h>

typedef __hip_bfloat16 bf16;
typedef float f32x4 __attribute__((ext_vector_type(4)));
typedef short bf16x8 __attribute__((ext_vector_type(8)));

#define HW 65536
#define NB 8

__device__ __forceinline__ bf16 f2b(float v){ return __float2bfloat16(v); }
__device__ __forceinline__ float b2f(bf16 v){ return __bfloat162float(v); }
__device__ __forceinline__ short fbits(float v){ bf16 b = f2b(v); return *(short*)&b; }

// conv3 B-pack: unit = ((br*2+half)*9 + ks)*6 + nc ; k_local = (lane>>4)*8+j -> c = half*32+k_local, tap = ks
__global__ void pack_w3(const float* __restrict__ wx, const float* __restrict__ wg,
                        short* __restrict__ dst)
{
    int idx = blockIdx.x * 256 + threadIdx.x;
    if (idx >= 110592) return;
    int unit = idx >> 9, r = idx & 511;
    int lane = r >> 3, j = r & 7;
    int nc = unit % 6; int u2 = unit / 6;
    int ks = u2 % 9;  int u3 = u2 / 9;
    int half = u3 & 1, br = u3 >> 1;
    int n = nc * 16 + (lane & 15);
    int c = half * 32 + ((lane >> 4) << 3) + j;
    const float* w = br ? wg : wx;
    dst[idx] = fbits((n < 81) ? w[n * 576 + c * 9 + ks] : 0.f);
}

// conv2 B-pack: unit = ((br*2+half)*5 + ks2)*2 + nc ; k = ks2*32+(lane>>4)*8+j -> tap=k>>4, c16=k&15
__global__ void pack_w2(const float* __restrict__ wx, const float* __restrict__ wg,
                        short* __restrict__ dst)
{
    int idx = blockIdx.x * 256 + threadIdx.x;
    if (idx >= 20480) return;
    int unit = idx >> 9, r = idx & 511;
    int lane = r >> 3, j = r & 7;
    int nc = unit & 1; int u2 = unit >> 1;
    int ks2 = u2 % 5; int u3 = u2 / 5;
    int half = u3 & 1, br = u3 >> 1;
    int n = half * 32 + nc * 16 + (lane & 15);
    int k = ks2 * 32 + ((lane >> 4) << 3) + j;
    int tap = k >> 4, c16 = k & 15;
    const float* w = br ? wg : wx;
    dst[idx] = fbits((tap < 9) ? w[n * 144 + c16 * 9 + tap] : 0.f);
}

__global__ void s_kernel(const float* __restrict__ out0, const float* __restrict__ d,
                         float* __restrict__ s)
{
    int i = blockIdx.x * 256 + threadIdx.x;
    s[i] = out0[i] - d[i];
}

// One dyn-filter branch per block: 16x16 output tile.
// conv1 (VALU) -> h1 ch-last -> [conv2 half-h MFMA -> conv3 half-h MFMA] x2
// -> register softmax + 9x9 filter. g-branch also writes d to out2.
// NOTE: no min-waves clamp — natural ~132 VGPR allows 3 waves/SIMD, matching
// the 3-blocks/CU LDS limit (41984 B). A forced (256,3) bound made the
// allocator spill the 96-reg accumulator (R8: FETCH 370MB, WRITE 1.2GB).
__global__ __launch_bounds__(256) void branch_kernel(
    const float* __restrict__ origin, const float* __restrict__ residual,
    const float* __restrict__ fxw1, const float* __restrict__ fxb1,
    const float* __restrict__ fxb2, const float* __restrict__ fxb3,
    const float* __restrict__ fgw1, const float* __restrict__ fgb1,
    const float* __restrict__ fgb2, const float* __restrict__ fgb3,
    const short* __restrict__ Bp2, const short* __restrict__ Bp3,
    bf16* __restrict__ pack, float* __restrict__ dout)
{
    __shared__ float s_src[576];       // 24x24 f32
    __shared__ bf16  s_h1[6720];       // [21 rows x 20][16ch], row 20 zero (K-pad)
    __shared__ bf16  s_h2[12960];      // [324][40] ch-last padded (32 used)

    const int t = threadIdx.x;
    const int lane = t & 63;
    const int w = t >> 6;
    const int g = lane >> 4;
    const int j16 = lane & 15;
    const int tile = blockIdx.x;
    const int br = blockIdx.y >> 3;
    const int img = blockIdx.y & 7;
    const int y0 = (tile >> 4) << 4, x0 = (tile & 15) << 4;
    const long ib = (long)img * HW;

    const float* w1 = br ? fgw1 : fxw1;
    const float* b1 = br ? fgb1 : fxb1;
    const float* b2 = br ? fgb2 : fxb2;
    const float* b3 = br ? fgb3 : fxb3;

    // ---- phase 1: stage src; g-branch also materializes d into out2 ----
    for (int idx = t; idx < 576; idx += 256) {
        int sy = idx / 24, sx = idx - sy * 24;
        int gy = y0 - 4 + sy, gx = x0 - 4 + sx;
        float v = 0.f;
        if ((unsigned)gy < 256u && (unsigned)gx < 256u) {
            long o = ib + (gy << 8) + gx;
            if (br) {
                v = origin[o] - residual[o];
                dout[o] = v;                    // idempotent overlap writes
            } else {
                v = residual[o];
            }
        }
        s_src[idx] = v;
    }
    __syncthreads();

    // ---- phase 2: conv1 (1->16) VALU -> h1 bf16 ch-last; zero K-pad row ----
    for (int p = t; p < 400; p += 256) {
        int py = p / 20, px = p - py * 20;
        int gy = y0 - 2 + py, gx = x0 - 2 + px;
        bool in = (unsigned)gy < 256u && (unsigned)gx < 256u;
        float sw[9];
        #pragma unroll
        for (int dy = 0; dy < 3; dy++)
            #pragma unroll
            for (int dx = 0; dx < 3; dx++)
                sw[dy * 3 + dx] = s_src[(py + 1 + dy) * 24 + px + 1 + dx];
        #pragma unroll
        for (int c = 0; c < 16; c++) {
            float a = b1[c];
            const float* wc = w1 + c * 9;
            #pragma unroll
            for (int q = 0; q < 9; q++) a = fmaf(wc[q], sw[q], a);
            s_h1[p * 16 + c] = f2b(in ? fmaxf(a, 0.f) : 0.f);
        }
    }
    for (int idx = t; idx < 320; idx += 256) s_h1[6400 + idx] = f2b(0.f);

    // ---- logits acc: 96 = 6 ncols x (4 rows/lane), persists across halves ----
    f32x4 acc[4][6];
    #pragma unroll
    for (int mr = 0; mr < 4; mr++)
        #pragma unroll
        for (int nc = 0; nc < 6; nc++) {
            int n = nc * 16 + j16;
            float bb = (n < 81) ? b3[n] : -1e30f;
            acc[mr][nc] = (f32x4){bb, bb, bb, bb};
        }
    __syncthreads();

    // ---- phases 3/4 per 32-channel half ----
    for (int h = 0; h < 2; h++) {
        // conv2 (16->64) MFMA: produce out-channels [h*32, h*32+32)
        {
            const short* Bw2 = Bp2 + (br * 2 + h) * 5120;
            bf16x8 B2[5][2];
            #pragma unroll
            for (int ks = 0; ks < 5; ks++)
                #pragma unroll
                for (int nc = 0; nc < 2; nc++)
                    B2[ks][nc] = *(const bf16x8*)(Bw2 + ((ks * 2 + nc) << 9) + lane * 8);
            const int kgh = g >> 1, c0 = (g & 1) * 8;
            for (int mrow = w; mrow < 21; mrow += 4) {
                int pA = mrow * 16 + j16;
                int pyA = pA / 18, pxA = pA - pyA * 18;
                f32x4 acc2[2];
                #pragma unroll
                for (int nc = 0; nc < 2; nc++) {
                    float bb = b2[h * 32 + nc * 16 + j16];
                    acc2[nc] = (f32x4){bb, bb, bb, bb};
                }
                #pragma unroll
                for (int ks = 0; ks < 5; ks++) {
                    int tap = 2 * ks + kgh;
                    int ty = (tap * 11) >> 5;
                    int tx = tap - ty * 3;
                    int pl = (pyA + ty) * 20 + pxA + tx;
                    if (pl > 419) pl = 419;          // pad-tap garbage row, B=0
                    bf16x8 A = *(const bf16x8*)&s_h1[pl * 16 + c0];
                    #pragma unroll
                    for (int nc = 0; nc < 2; nc++)
                        acc2[nc] = __builtin_amdgcn_mfma_f32_16x16x32_bf16(A, B2[ks][nc], acc2[nc], 0, 0, 0);
                }
                #pragma unroll
                for (int nc = 0; nc < 2; nc++) {
                    int ch = nc * 16 + j16;
                    #pragma unroll
                    for (int r = 0; r < 4; r++) {
                        int p = mrow * 16 + g * 4 + r;
                        if (p < 324)
                            s_h2[p * 40 + ch] = f2b(fmaxf(acc2[nc][r], 0.f));
                    }
                }
            }
        }
        __syncthreads();

        // conv3 (64->81) MFMA: accumulate K-slice c in [h*32, h*32+32)
        {
            const short* Bw3 = Bp3 + (br * 2 + h) * 27648;
            for (int ks = 0; ks < 9; ks++) {
                bf16x8 B3[6];
                #pragma unroll
                for (int nc = 0; nc < 6; nc++)
                    B3[nc] = *(const bf16x8*)(Bw3 + ((ks * 6 + nc) << 9) + lane * 8);
                int dy = (ks * 11) >> 5;
                int dx = ks - dy * 3;
                #pragma unroll
                for (int mr = 0; mr < 4; mr++) {
                    int mrow = w * 4 + mr;
                    int pl = (mrow + dy) * 18 + j16 + dx;
                    bf16x8 A = *(const bf16x8*)&s_h2[pl * 40 + g * 8];
                    #pragma unroll
                    for (int nc = 0; nc < 6; nc++)
                        acc[mr][nc] = __builtin_amdgcn_mfma_f32_16x16x32_bf16(A, B3[nc], acc[mr][nc], 0, 0, 0);
                }
            }
        }
        __syncthreads();
    }

    // ---- phase 5: register softmax (16 lanes x 6 ncols) + 9x9 filter ----
    int ti[6], tj[6];
    #pragma unroll
    for (int nc = 0; nc < 6; nc++) {
        int n = nc * 16 + j16;
        int tt = n / 9;
        ti[nc] = tt; tj[nc] = n - tt * 9;
    }
    #pragma unroll
    for (int mr = 0; mr < 4; mr++) {
        int mrow = w * 4 + mr;
        bf16 res[4];
        #pragma unroll
        for (int r = 0; r < 4; r++) {
            float mx = -1e30f;
            #pragma unroll
            for (int nc = 0; nc < 6; nc++) mx = fmaxf(mx, acc[mr][nc][r]);
            #pragma unroll
            for (int msk = 1; msk < 16; msk <<= 1) mx = fmaxf(mx, __shfl_xor(mx, msk));
            float ssum = 0.f, fsum = 0.f;
            int px = g * 4 + r;
            #pragma unroll
            for (int nc = 0; nc < 6; nc++) {
                float e = __expf(acc[mr][nc][r] - mx);   // pads: exp(-1e30) = 0
                ssum += e;
                int idx = (mrow + ti[nc]) * 24 + px + tj[nc];
                fsum += e * s_src[idx > 575 ? 575 : idx];
            }
            #pragma unroll
            for (int msk = 1; msk < 16; msk <<= 1) {
                ssum += __shfl_xor(ssum, msk);
                fsum += __shfl_xor(fsum, msk);
            }
            res[r] = f2b(fsum / ssum);
        }
        if (j16 == 0) {
            long base = ((long)(img * 2 + br) << 16) + ((y0 + mrow) << 8) + x0 + g * 4;
            pack[base + 0] = res[0];
            pack[base + 1] = res[1];
            pack[base + 2] = res[2];
            pack[base + 3] = res[3];
        }
    }
}

// c1(2->64)+c2(64->1) fused per tile, 2 barriers total; out0 = s + d
__global__ __launch_bounds__(256) void tail_kernel(
    const bf16* __restrict__ pack,
    const float* __restrict__ c1w, const float* __restrict__ c1b,
    const float* __restrict__ c2w, const float* __restrict__ c2b,
    const float* __restrict__ d2, float* __restrict__ out0)
{
    __shared__ float s_x[400], s_g[400];   // 20x20
    __shared__ bf16  s_h[22680];           // [324][70] (64 used; 70 => 2-way banks)

    const int t = threadIdx.x;
    const int tile = blockIdx.x;
    const int img = blockIdx.y;
    const int y0 = (tile >> 4) << 4, x0 = (tile & 15) << 4;

    for (int idx = t; idx < 400; idx += 256) {
        int hy = idx / 20, hx = idx - hy * 20;
        int gy = y0 - 2 + hy, gx = x0 - 2 + hx;
        float vx = 0.f, vg = 0.f;
        if ((unsigned)gy < 256u && (unsigned)gx < 256u) {
            int o = (gy << 8) + gx;
            vx = b2f(pack[((img * 2 + 0) << 16) + o]);
            vg = b2f(pack[((img * 2 + 1) << 16) + o]);
        }
        s_x[idx] = vx;
        s_g[idx] = vg;
    }
    __syncthreads();

    // produce: c1 for all 64 channels of each pixel
    for (int p = t; p < 324; p += 256) {
        int hy = p / 18, hx = p - hy * 18;
        int gy = y0 - 1 + hy, gx = x0 - 1 + hx;
        bool in = (unsigned)gy < 256u && (unsigned)gx < 256u;
        float sx[9], sg[9];
        #pragma unroll
        for (int dy = 0; dy < 3; dy++)
            #pragma unroll
            for (int dx = 0; dx < 3; dx++) {
                sx[dy * 3 + dx] = s_x[(hy + dy) * 20 + hx + dx];
                sg[dy * 3 + dx] = s_g[(hy + dy) * 20 + hx + dx];
            }
        for (int c = 0; c < 64; c++) {
            float a = c1b[c];
            const float* wp = c1w + c * 18;
            #pragma unroll
            for (int q = 0; q < 9; q++) {
                a = fmaf(wp[q], sx[q], a);
                a = fmaf(wp[9 + q], sg[q], a);
            }
            s_h[p * 70 + c] = f2b(in ? fmaxf(a, 0.f) : 0.f);
        }
    }
    __syncthreads();

    // consume: c2 (64ch x 9 taps) via u32 pair reads + bf16 bit-unpack
    const int ly = t >> 4, lx = t & 15;
    float sacc = c2b[0];
    #pragma unroll
    for (int t9 = 0; t9 < 9; t9++) {
        int pl = (ly + t9 / 3) * 18 + lx + (t9 % 3);
        const bf16* rowp = s_h + pl * 70;
        #pragma unroll
        for (int c = 0; c < 64; c += 2) {
            unsigned int u = *(const unsigned int*)&rowp[c];
            float flo = __uint_as_float(u << 16);
            float fhi = __uint_as_float(u & 0xffff0000u);
            sacc = fmaf(c2w[c * 9 + t9],       flo, sacc);
            sacc = fmaf(c2w[(c + 1) * 9 + t9], fhi, sacc);
        }
    }
    long o = (long)img * HW + ((y0 + ly) << 8) + (x0 + lx);
    out0[o] = sacc + d2[o];
}

extern "C" void kernel_launch(void* const* d_in, const int* in_sizes, int n_in,
                              void* d_out, int out_size, void* d_ws, size_t ws_size,
                              hipStream_t stream)
{
    const float* origin   = (const float*)d_in[0];
    const float* residual = (const float*)d_in[1];
    const float* fxw1 = (const float*)d_in[2];  const float* fxb1 = (const float*)d_in[3];
    const float* fxw2 = (const float*)d_in[4];  const float* fxb2 = (const float*)d_in[5];
    const float* fxw3 = (const float*)d_in[6];  const float* fxb3 = (const float*)d_in[7];
    const float* fgw1 = (const float*)d_in[8];  const float* fgb1 = (const float*)d_in[9];
    const float* fgw2 = (const float*)d_in[10]; const float* fgb2 = (const float*)d_in[11];
    const float* fgw3 = (const float*)d_in[12]; const float* fgb3 = (const float*)d_in[13];
    const float* c1w  = (const float*)d_in[14]; const float* c1b  = (const float*)d_in[15];
    const float* c2w  = (const float*)d_in[16]; const float* c2b  = (const float*)d_in[17];

    float* out0 = (float*)d_out;                 // out = s + d
    float* out1 = out0 + (long)NB * HW;          // s (temp: packed bf16 x_/g_)
    float* out2 = out1 + (long)NB * HW;          // d
    bf16*  pack = (bf16*)out1;

    short* Bp2 = (short*)d_ws;                   // 20480 shorts
    short* Bp3 = Bp2 + 20480;                    // 110592 shorts

    pack_w2<<<80, 256, 0, stream>>>(fxw2, fgw2, Bp2);
    pack_w3<<<432, 256, 0, stream>>>(fxw3, fgw3, Bp3);

    branch_kernel<<<dim3(256, 16), 256, 0, stream>>>(
        origin, residual,
        fxw1, fxb1, fxb2, fxb3,
        fgw1, fgb1, fgb2, fgb3,
        Bp2, Bp3, pack, out2);

    tail_kernel<<<dim3(256, 8), 256, 0, stream>>>(pack, c1w, c1b, c2w, c2b, out2, out0);

    s_kernel<<<(NB * HW) / 256, 256, 0, stream>>>(out0, out2, out1);
}

// Round 10
// 417.290 us; speedup vs baseline: 1.4200x; 1.2150x over previous
//
#include <hip/hip_runtime.h>
#include <hip/hip_bf16.h>

typedef __hip_bfloat16 bf16;
typedef float f32x4 __attribute__((ext_vector_type(4)));
typedef short bf16x8 __attribute__((ext_vector_type(8)));
typedef _Float16 f16x2 __attribute__((ext_vector_type(2)));

#define HW 65536
#define NB 8

__device__ __forceinline__ bf16 f2b(float v){ return __float2bfloat16(v); }
__device__ __forceinline__ float b2f(bf16 v){ return __bfloat162float(v); }
__device__ __forceinline__ unsigned short fbits(float v){ bf16 b = f2b(v); return *(unsigned short*)&b; }
__device__ __forceinline__ unsigned int pk2(float a, float b){
    return (unsigned int)fbits(a) | ((unsigned int)fbits(b) << 16);
}
__device__ __forceinline__ float dot2h(f16x2 a, f16x2 b, float c){
#if __has_builtin(__builtin_amdgcn_fdot2)
    return __builtin_amdgcn_fdot2(a, b, c, false);
#else
    return c + (float)a[0]*(float)b[0] + (float)a[1]*(float)b[1];
#endif
}

// conv3 A-pack (weights as MFMA-A, m=tap, k=ch-in-half):
// unit = ((br*2+half)*9 + ks)*6 + mt ; line element: tap = mt*16+(lane&15), c = half*32+(lane>>4)*8+j
__global__ void pack_w3(const float* __restrict__ wx, const float* __restrict__ wg,
                        short* __restrict__ dst)
{
    int idx = blockIdx.x * 256 + threadIdx.x;
    if (idx >= 110592) return;
    int unit = idx >> 9, r = idx & 511;
    int lane = r >> 3, j = r & 7;
    int mt = unit % 6; int u2 = unit / 6;
    int ks = u2 % 9;  int u3 = u2 / 9;
    int half = u3 & 1, br = u3 >> 1;
    int n = mt * 16 + (lane & 15);
    int c = half * 32 + ((lane >> 4) << 3) + j;
    const float* w = br ? wg : wx;
    dst[idx] = fbits((n < 81) ? w[n * 576 + c * 9 + ks] : 0.f);
}

// conv2 A-pack: unit = ((br*2+half)*5 + ks)*2 + mt2 ; ch = half*32+mt2*16+(lane&15), k = ks*32+(lane>>4)*8+j
__global__ void pack_w2(const float* __restrict__ wx, const float* __restrict__ wg,
                        short* __restrict__ dst)
{
    int idx = blockIdx.x * 256 + threadIdx.x;
    if (idx >= 20480) return;
    int unit = idx >> 9, r = idx & 511;
    int lane = r >> 3, j = r & 7;
    int mt2 = unit & 1; int u2 = unit >> 1;
    int ks = u2 % 5; int u3 = u2 / 5;
    int half = u3 & 1, br = u3 >> 1;
    int n = half * 32 + mt2 * 16 + (lane & 15);
    int k = ks * 32 + ((lane >> 4) << 3) + j;
    int tap = k >> 4, c16 = k & 15;
    const float* w = br ? wg : wx;
    dst[idx] = fbits((tap < 9) ? w[n * 144 + c16 * 9 + tap] : 0.f);
}

// tail weight pairing: c1wp[c*9+q] = (wx, wg); c2wp[t9*32+cp] = (w[2cp], w[2cp+1])
__global__ void pack_c12(const float* __restrict__ c1w, const float* __restrict__ c2w,
                         f16x2* __restrict__ c1wp, f16x2* __restrict__ c2wp)
{
    int idx = blockIdx.x * 256 + threadIdx.x;
    if (idx < 576) {
        int c = idx / 9, q = idx - c * 9;
        c1wp[idx] = (f16x2){(_Float16)c1w[c * 18 + q], (_Float16)c1w[c * 18 + 9 + q]};
    } else if (idx < 864) {
        int i = idx - 576;
        int t9 = i >> 5, cp = i & 31;
        c2wp[i] = (f16x2){(_Float16)c2w[(2 * cp) * 9 + t9], (_Float16)c2w[(2 * cp + 1) * 9 + t9]};
    }
}

__global__ void s_kernel(const float* __restrict__ out0, const float* __restrict__ d,
                         float* __restrict__ s)
{
    int i = blockIdx.x * 256 + threadIdx.x;
    s[i] = out0[i] - d[i];
}

// One dyn-filter branch per block: 16x16 output tile. Transposed GEMMs:
// m = feature (ch / tap), n = pixel. D rows = features -> packed conv2 stores,
// 4-lane softmax reduce, coalesced output.
__global__ __launch_bounds__(256) void branch_kernel(
    const float* __restrict__ origin, const float* __restrict__ residual,
    const float* __restrict__ fxw1, const float* __restrict__ fxb1,
    const float* __restrict__ fxb2, const float* __restrict__ fxb3,
    const float* __restrict__ fgw1, const float* __restrict__ fgb1,
    const float* __restrict__ fgb2, const float* __restrict__ fgb3,
    const short* __restrict__ Bp2, const short* __restrict__ Bp3,
    bf16* __restrict__ pack, float* __restrict__ dout)
{
    __shared__ bf16 s_srcb[576];      // 24x24 bf16
    __shared__ bf16 s_h1[6720];       // [21x20 px][16ch], rows 400..419 zero (K-pad)
    __shared__ bf16 s_h2[12960];      // [324 px][40] ch-last (32 used, current half)

    const int t = threadIdx.x;
    const int lane = t & 63;
    const int w = t >> 6;
    const int g = lane >> 4;
    const int j16 = lane & 15;
    const int tile = blockIdx.x;
    const int br = blockIdx.y >> 3;
    const int img = blockIdx.y & 7;
    const int y0 = (tile >> 4) << 4, x0 = (tile & 15) << 4;
    const long ib = (long)img * HW;

    const float* w1 = br ? fgw1 : fxw1;
    const float* b1 = br ? fgb1 : fxb1;
    const float* b2 = br ? fgb2 : fxb2;
    const float* b3 = br ? fgb3 : fxb3;

    // ---- phase 1: stage src (bf16); g-branch also materializes d (f32 exact) ----
    for (int idx = t; idx < 576; idx += 256) {
        int sy = idx / 24, sx = idx - sy * 24;
        int gy = y0 - 4 + sy, gx = x0 - 4 + sx;
        float v = 0.f;
        if ((unsigned)gy < 256u && (unsigned)gx < 256u) {
            long o = ib + (gy << 8) + gx;
            if (br) { v = origin[o] - residual[o]; dout[o] = v; }
            else    { v = residual[o]; }
        }
        s_srcb[idx] = f2b(v);
    }
    __syncthreads();

    // ---- phase 2: conv1 (1->16) VALU -> h1 ch-last; zero K-pad rows ----
    for (int p = t; p < 400; p += 256) {
        int py = p / 20, px = p - py * 20;
        int gy = y0 - 2 + py, gx = x0 - 2 + px;
        bool in = (unsigned)gy < 256u && (unsigned)gx < 256u;
        float sw[9];
        #pragma unroll
        for (int dy = 0; dy < 3; dy++)
            #pragma unroll
            for (int dx = 0; dx < 3; dx++)
                sw[dy * 3 + dx] = b2f(s_srcb[(py + 1 + dy) * 24 + px + 1 + dx]);
        #pragma unroll
        for (int c = 0; c < 16; c++) {
            float a = b1[c];
            const float* wc = w1 + c * 9;
            #pragma unroll
            for (int q = 0; q < 9; q++) a = fmaf(wc[q], sw[q], a);
            s_h1[p * 16 + c] = f2b(in ? fmaxf(a, 0.f) : 0.f);
        }
    }
    for (int idx = t; idx < 320; idx += 256) s_h1[6400 + idx] = f2b(0.f);

    // ---- logits acc[6 m-tiles][4 n-tiles]; lane holds taps mt*16+g*4+r of px (w*4+nr, j16) ----
    f32x4 acc[6][4];
    #pragma unroll
    for (int mt = 0; mt < 5; mt++) {
        f32x4 bv = *(const f32x4*)&b3[mt * 16 + (g << 2)];
        #pragma unroll
        for (int nr = 0; nr < 4; nr++) acc[mt][nr] = bv;
    }
    {
        float e0 = (g == 0) ? b3[80] : -1e30f;
        f32x4 bv = (f32x4){e0, -1e30f, -1e30f, -1e30f};
        #pragma unroll
        for (int nr = 0; nr < 4; nr++) acc[5][nr] = bv;
    }
    __syncthreads();

    // ---- phases 3/4 per 32-channel half ----
    for (int h = 0; h < 2; h++) {
        // conv2: D[ch][px]; A=weights, B=h1 pixels. N=336 (21 n-tiles), M=32 (2), K=160 (5)
        {
            const short* Aw2 = Bp2 + (br * 2 + h) * 5120;
            const int kgh = g >> 1, c0 = (g & 1) * 8;
            for (int nt = w; nt < 21; nt += 4) {
                int p = nt * 16 + j16;
                int py = p / 18, px = p - py * 18;
                f32x4 acc2[2];
                #pragma unroll
                for (int mt2 = 0; mt2 < 2; mt2++)
                    acc2[mt2] = *(const f32x4*)&b2[h * 32 + mt2 * 16 + (g << 2)];
                #pragma unroll
                for (int ks = 0; ks < 5; ks++) {
                    int tap = 2 * ks + kgh;
                    int ty = (tap * 11) >> 5;
                    int tx = tap - ty * 3;
                    int pl = (py + ty) * 20 + px + tx;
                    if (pl > 419) pl = 419;          // pad-tap garbage, A=0 there
                    bf16x8 B = *(const bf16x8*)&s_h1[pl * 16 + c0];
                    #pragma unroll
                    for (int mt2 = 0; mt2 < 2; mt2++) {
                        bf16x8 A = *(const bf16x8*)(Aw2 + ((ks * 2 + mt2) << 9) + lane * 8);
                        acc2[mt2] = __builtin_amdgcn_mfma_f32_16x16x32_bf16(A, B, acc2[mt2], 0, 0, 0);
                    }
                }
                if (p < 324) {
                    #pragma unroll
                    for (int mt2 = 0; mt2 < 2; mt2++) {
                        unsigned int lo = pk2(fmaxf(acc2[mt2][0], 0.f), fmaxf(acc2[mt2][1], 0.f));
                        unsigned int hi = pk2(fmaxf(acc2[mt2][2], 0.f), fmaxf(acc2[mt2][3], 0.f));
                        *(uint2*)((char*)s_h2 + (p * 40 + mt2 * 16 + (g << 2)) * 2) = (uint2){lo, hi};
                    }
                }
            }
        }
        __syncthreads();

        // conv3: D[tap][px]; A=w3, B=h2 pixels. 9 k-steps (taps) x K=32 ch
        {
            const short* Aw3 = Bp3 + (br * 2 + h) * 27648;
            #pragma unroll
            for (int ks = 0; ks < 9; ks++) {
                const int dy = (ks * 11) >> 5;
                const int dx = ks - dy * 3;
                bf16x8 Bf[4];
                #pragma unroll
                for (int nr = 0; nr < 4; nr++) {
                    int pl = (w * 4 + nr + dy) * 18 + j16 + dx;
                    Bf[nr] = *(const bf16x8*)&s_h2[pl * 40 + (g << 3)];
                }
                #pragma unroll
                for (int mt = 0; mt < 6; mt++) {
                    bf16x8 A = *(const bf16x8*)(Aw3 + ((ks * 6 + mt) << 9) + lane * 8);
                    #pragma unroll
                    for (int nr = 0; nr < 4; nr++)
                        acc[mt][nr] = __builtin_amdgcn_mfma_f32_16x16x32_bf16(A, Bf[nr], acc[mt][nr], 0, 0, 0);
                }
            }
        }
        __syncthreads();
    }

    // ---- phase 5: softmax over 96 taps (24/lane x 4 g-lanes) + 9x9 filter ----
    #pragma unroll
    for (int nr = 0; nr < 4; nr++) {
        const int nrow = w * 4 + nr;
        float mx = -1e30f;
        #pragma unroll
        for (int mt = 0; mt < 6; mt++)
            #pragma unroll
            for (int r = 0; r < 4; r++) mx = fmaxf(mx, acc[mt][nr][r]);
        mx = fmaxf(mx, __shfl_xor(mx, 16));
        mx = fmaxf(mx, __shfl_xor(mx, 32));
        float ssum = 0.f, fsum = 0.f;
        #pragma unroll
        for (int mt = 0; mt < 6; mt++)
            #pragma unroll
            for (int r = 0; r < 4; r++) {
                int tap = mt * 16 + (g << 2) + r;
                float e = __expf(acc[mt][nr][r] - mx);   // pads -> 0
                ssum += e;
                int ti = (tap * 57) >> 9;                // tap/9 for tap<96
                int tj = tap - ti * 9;
                int idx = (nrow + ti) * 24 + j16 + tj;
                fsum += e * b2f(s_srcb[idx > 575 ? 575 : idx]);
            }
        ssum += __shfl_xor(ssum, 16);
        ssum += __shfl_xor(ssum, 32);
        fsum += __shfl_xor(fsum, 16);
        fsum += __shfl_xor(fsum, 32);
        if (g == 0)
            pack[((long)(img * 2 + br) << 16) + ((y0 + nrow) << 8) + x0 + j16] = f2b(fsum / ssum);
    }
}

// c1(2->64)+c2(64->1) fused per tile via fp16 dot2; out0 = s + d
__global__ __launch_bounds__(256) void tail_kernel(
    const bf16* __restrict__ pack,
    const f16x2* __restrict__ c1wp, const float* __restrict__ c1b,
    const f16x2* __restrict__ c2wp, const float* __restrict__ c2b,
    const float* __restrict__ d2, float* __restrict__ out0)
{
    __shared__ f16x2 s_xg[400];            // 20x20 of (x_, g_)
    __shared__ _Float16 s_h[22680];        // [324][70] (64 used)

    const int t = threadIdx.x;
    const int tile = blockIdx.x;
    const int img = blockIdx.y;
    const int y0 = (tile >> 4) << 4, x0 = (tile & 15) << 4;

    for (int idx = t; idx < 400; idx += 256) {
        int hy = idx / 20, hx = idx - hy * 20;
        int gy = y0 - 2 + hy, gx = x0 - 2 + hx;
        float vx = 0.f, vg = 0.f;
        if ((unsigned)gy < 256u && (unsigned)gx < 256u) {
            int o = (gy << 8) + gx;
            vx = b2f(pack[((img * 2 + 0) << 16) + o]);
            vg = b2f(pack[((img * 2 + 1) << 16) + o]);
        }
        s_xg[idx] = (f16x2){(_Float16)vx, (_Float16)vg};
    }
    __syncthreads();

    // produce: c1 (fp16 dot2, 9 per channel)
    for (int p = t; p < 324; p += 256) {
        int hy = p / 18, hx = p - hy * 18;
        int gy = y0 - 1 + hy, gx = x0 - 1 + hx;
        bool in = (unsigned)gy < 256u && (unsigned)gx < 256u;
        f16x2 sw[9];
        #pragma unroll
        for (int dy = 0; dy < 3; dy++)
            #pragma unroll
            for (int dx = 0; dx < 3; dx++)
                sw[dy * 3 + dx] = s_xg[(hy + dy) * 20 + hx + dx];
        for (int c = 0; c < 64; c++) {
            float a = c1b[c];
            const f16x2* wp = c1wp + c * 9;
            #pragma unroll
            for (int q = 0; q < 9; q++) a = dot2h(sw[q], wp[q], a);
            s_h[p * 70 + c] = (_Float16)(in ? fmaxf(a, 0.f) : 0.f);
        }
    }
    __syncthreads();

    // consume: c2 = 9 taps x 32 ch-pairs of dot2
    const int ly = t >> 4, lx = t & 15;
    float sacc = c2b[0];
    #pragma unroll
    for (int t9 = 0; t9 < 9; t9++) {
        int pl = (ly + t9 / 3) * 18 + lx + (t9 % 3);
        const _Float16* rowp = s_h + pl * 70;
        const f16x2* wrow = c2wp + t9 * 32;
        #pragma unroll
        for (int cp = 0; cp < 32; cp++) {
            f16x2 hv = *(const f16x2*)&rowp[2 * cp];
            sacc = dot2h(hv, wrow[cp], sacc);
        }
    }
    long o = (long)img * HW + ((y0 + ly) << 8) + (x0 + lx);
    out0[o] = sacc + d2[o];
}

extern "C" void kernel_launch(void* const* d_in, const int* in_sizes, int n_in,
                              void* d_out, int out_size, void* d_ws, size_t ws_size,
                              hipStream_t stream)
{
    const float* origin   = (const float*)d_in[0];
    const float* residual = (const float*)d_in[1];
    const float* fxw1 = (const float*)d_in[2];  const float* fxb1 = (const float*)d_in[3];
    const float* fxw2 = (const float*)d_in[4];  const float* fxb2 = (const float*)d_in[5];
    const float* fxw3 = (const float*)d_in[6];  const float* fxb3 = (const float*)d_in[7];
    const float* fgw1 = (const float*)d_in[8];  const float* fgb1 = (const float*)d_in[9];
    const float* fgw2 = (const float*)d_in[10]; const float* fgb2 = (const float*)d_in[11];
    const float* fgw3 = (const float*)d_in[12]; const float* fgb3 = (const float*)d_in[13];
    const float* c1w  = (const float*)d_in[14]; const float* c1b  = (const float*)d_in[15];
    const float* c2w  = (const float*)d_in[16]; const float* c2b  = (const float*)d_in[17];

    float* out0 = (float*)d_out;                 // out = s + d
    float* out1 = out0 + (long)NB * HW;          // s (temp: packed bf16 x_/g_)
    float* out2 = out1 + (long)NB * HW;          // d
    bf16*  pack = (bf16*)out1;

    short* Bp2 = (short*)d_ws;                   // 20480 shorts
    short* Bp3 = Bp2 + 20480;                    // 110592 shorts
    f16x2* c1wp = (f16x2*)(Bp3 + 110592);        // 576 pairs
    f16x2* c2wp = c1wp + 576;                    // 288 pairs

    pack_w2<<<80, 256, 0, stream>>>(fxw2, fgw2, Bp2);
    pack_w3<<<432, 256, 0, stream>>>(fxw3, fgw3, Bp3);
    pack_c12<<<4, 256, 0, stream>>>(c1w, c2w, c1wp, c2wp);

    branch_kernel<<<dim3(256, 16), 256, 0, stream>>>(
        origin, residual,
        fxw1, fxb1, fxb2, fxb3,
        fgw1, fgb1, fgb2, fgb3,
        Bp2, Bp3, pack, out2);

    tail_kernel<<<dim3(256, 8), 256, 0, stream>>>(pack, c1wp, c1b, c2wp, c2b, out2, out0);

    s_kernel<<<(NB * HW) / 256, 256, 0, stream>>>(out0, out2, out1);
}

// Round 11
// 352.674 us; speedup vs baseline: 1.6802x; 1.1832x over previous
//
#include <hip/hip_runtime.h>
#include <hip/hip_bf16.h>

typedef __hip_bfloat16 bf16;
typedef float f32x4 __attribute__((ext_vector_type(4)));
typedef short bf16x8 __attribute__((ext_vector_type(8)));
typedef _Float16 f16x2 __attribute__((ext_vector_type(2)));

#define HW 65536
#define NB 8

__device__ __forceinline__ bf16 f2b(float v){ return __float2bfloat16(v); }
__device__ __forceinline__ float b2f(bf16 v){ return __bfloat162float(v); }
__device__ __forceinline__ unsigned short fbits(float v){ bf16 b = f2b(v); return *(unsigned short*)&b; }
__device__ __forceinline__ unsigned int pk2(float a, float b){
    return (unsigned int)fbits(a) | ((unsigned int)fbits(b) << 16);
}
__device__ __forceinline__ float dot2h(f16x2 a, f16x2 b, float c){
#if __has_builtin(__builtin_amdgcn_fdot2)
    return __builtin_amdgcn_fdot2(a, b, c, false);
#else
    return c + (float)a[0]*(float)b[0] + (float)a[1]*(float)b[1];
#endif
}

// conv3 A-pack (weights as MFMA-A, m=tap, k=ch-in-half):
// unit = ((br*2+half)*9 + ks)*6 + mt ; tap = mt*16+(lane&15), c = half*32+(lane>>4)*8+j
__global__ void pack_w3(const float* __restrict__ wx, const float* __restrict__ wg,
                        short* __restrict__ dst)
{
    int idx = blockIdx.x * 256 + threadIdx.x;
    if (idx >= 110592) return;
    int unit = idx >> 9, r = idx & 511;
    int lane = r >> 3, j = r & 7;
    int mt = unit % 6; int u2 = unit / 6;
    int ks = u2 % 9;  int u3 = u2 / 9;
    int half = u3 & 1, br = u3 >> 1;
    int n = mt * 16 + (lane & 15);
    int c = half * 32 + ((lane >> 4) << 3) + j;
    const float* w = br ? wg : wx;
    dst[idx] = fbits((n < 81) ? w[n * 576 + c * 9 + ks] : 0.f);
}

// conv2 A-pack: unit = ((br*2+half)*5 + ks)*2 + mt2 ; ch = half*32+mt2*16+(lane&15), k = ks*32+(lane>>4)*8+j
__global__ void pack_w2(const float* __restrict__ wx, const float* __restrict__ wg,
                        short* __restrict__ dst)
{
    int idx = blockIdx.x * 256 + threadIdx.x;
    if (idx >= 20480) return;
    int unit = idx >> 9, r = idx & 511;
    int lane = r >> 3, j = r & 7;
    int mt2 = unit & 1; int u2 = unit >> 1;
    int ks = u2 % 5; int u3 = u2 / 5;
    int half = u3 & 1, br = u3 >> 1;
    int n = half * 32 + mt2 * 16 + (lane & 15);
    int k = ks * 32 + ((lane >> 4) << 3) + j;
    int tap = k >> 4, c16 = k & 15;
    const float* w = br ? wg : wx;
    dst[idx] = fbits((tap < 9) ? w[n * 144 + c16 * 9 + tap] : 0.f);
}

// tail weight pairing: c1wp[c*9+q] = (wx, wg); c2wp[t9*32+cp] = (w[2cp], w[2cp+1])
__global__ void pack_c12(const float* __restrict__ c1w, const float* __restrict__ c2w,
                         f16x2* __restrict__ c1wp, f16x2* __restrict__ c2wp)
{
    int idx = blockIdx.x * 256 + threadIdx.x;
    if (idx < 576) {
        int c = idx / 9, q = idx - c * 9;
        c1wp[idx] = (f16x2){(_Float16)c1w[c * 18 + q], (_Float16)c1w[c * 18 + 9 + q]};
    } else if (idx < 864) {
        int i = idx - 576;
        int t9 = i >> 5, cp = i & 31;
        c2wp[i] = (f16x2){(_Float16)c2w[(2 * cp) * 9 + t9], (_Float16)c2w[(2 * cp + 1) * 9 + t9]};
    }
}

__global__ void s_kernel(const float* __restrict__ out0, const float* __restrict__ d,
                         float* __restrict__ s)
{
    int i = blockIdx.x * 256 + threadIdx.x;
    s[i] = out0[i] - d[i];
}

// One dyn-filter branch per block: 16x16 output tile, 512 threads (8 waves).
// Each wave owns 2 n-tiles -> acc[6][2] = 48 regs/thread (R10's acc[6][4]=96
// pushed unified VGPR+AGPR to ~228 -> 2 waves/SIMD; this targets <=128 -> 4).
__global__ __launch_bounds__(512) void branch_kernel(
    const float* __restrict__ origin, const float* __restrict__ residual,
    const float* __restrict__ fxw1, const float* __restrict__ fxb1,
    const float* __restrict__ fxb2, const float* __restrict__ fxb3,
    const float* __restrict__ fgw1, const float* __restrict__ fgb1,
    const float* __restrict__ fgb2, const float* __restrict__ fgb3,
    const short* __restrict__ Bp2, const short* __restrict__ Bp3,
    bf16* __restrict__ pack, float* __restrict__ dout)
{
    __shared__ bf16 s_srcb[576];      // 24x24 bf16
    __shared__ bf16 s_h1[6720];       // [21x20 px][16ch], rows 400..419 zero (K-pad)
    __shared__ bf16 s_h2[12960];      // [324 px][40] ch-last (32 used, current half)

    const int t = threadIdx.x;
    const int lane = t & 63;
    const int w = t >> 6;             // wave 0..7
    const int g = lane >> 4;
    const int j16 = lane & 15;
    const int tile = blockIdx.x;
    const int br = blockIdx.y >> 3;
    const int img = blockIdx.y & 7;
    const int y0 = (tile >> 4) << 4, x0 = (tile & 15) << 4;
    const long ib = (long)img * HW;

    const float* w1 = br ? fgw1 : fxw1;
    const float* b1 = br ? fgb1 : fxb1;
    const float* b2 = br ? fgb2 : fxb2;
    const float* b3 = br ? fgb3 : fxb3;

    // ---- phase 1: stage src (bf16); g-branch also materializes d (f32 exact) ----
    for (int idx = t; idx < 576; idx += 512) {
        int sy = idx / 24, sx = idx - sy * 24;
        int gy = y0 - 4 + sy, gx = x0 - 4 + sx;
        float v = 0.f;
        if ((unsigned)gy < 256u && (unsigned)gx < 256u) {
            long o = ib + (gy << 8) + gx;
            if (br) { v = origin[o] - residual[o]; dout[o] = v; }
            else    { v = residual[o]; }
        }
        s_srcb[idx] = f2b(v);
    }
    __syncthreads();

    // ---- phase 2: conv1 (1->16) VALU -> h1 ch-last; zero K-pad rows ----
    if (t < 400) {
        int p = t;
        int py = p / 20, px = p - py * 20;
        int gy = y0 - 2 + py, gx = x0 - 2 + px;
        bool in = (unsigned)gy < 256u && (unsigned)gx < 256u;
        float sw[9];
        #pragma unroll
        for (int dy = 0; dy < 3; dy++)
            #pragma unroll
            for (int dx = 0; dx < 3; dx++)
                sw[dy * 3 + dx] = b2f(s_srcb[(py + 1 + dy) * 24 + px + 1 + dx]);
        #pragma unroll
        for (int c = 0; c < 16; c++) {
            float a = b1[c];
            const float* wc = w1 + c * 9;
            #pragma unroll
            for (int q = 0; q < 9; q++) a = fmaf(wc[q], sw[q], a);
            s_h1[p * 16 + c] = f2b(in ? fmaxf(a, 0.f) : 0.f);
        }
    } else if (t < 400 + 320) {
        s_h1[6400 + (t - 400)] = f2b(0.f);
    }

    // ---- logits acc[6 m-tiles][2 n-tiles]; lane: taps mt*16+g*4+r of px (w*2+nr, j16) ----
    f32x4 acc[6][2];
    #pragma unroll
    for (int mt = 0; mt < 5; mt++) {
        f32x4 bv = *(const f32x4*)&b3[mt * 16 + (g << 2)];
        acc[mt][0] = bv; acc[mt][1] = bv;
    }
    {
        float e0 = (g == 0) ? b3[80] : -1e30f;
        f32x4 bv = (f32x4){e0, -1e30f, -1e30f, -1e30f};
        acc[5][0] = bv; acc[5][1] = bv;
    }
    __syncthreads();

    // ---- phases 3/4 per 32-channel half ----
    for (int h = 0; h < 2; h++) {
        // conv2: D[ch][px]; A=weights, B=h1 pixels. 21 n-tiles over 8 waves
        {
            const short* Aw2 = Bp2 + (br * 2 + h) * 5120;
            const int kgh = g >> 1, c0 = (g & 1) * 8;
            for (int nt = w; nt < 21; nt += 8) {
                int p = nt * 16 + j16;
                int py = p / 18, px = p - py * 18;
                f32x4 acc2[2];
                #pragma unroll
                for (int mt2 = 0; mt2 < 2; mt2++)
                    acc2[mt2] = *(const f32x4*)&b2[h * 32 + mt2 * 16 + (g << 2)];
                #pragma unroll
                for (int ks = 0; ks < 5; ks++) {
                    int tap = 2 * ks + kgh;
                    int ty = (tap * 11) >> 5;
                    int tx = tap - ty * 3;
                    int pl = (py + ty) * 20 + px + tx;
                    if (pl > 419) pl = 419;          // pad-tap garbage, A=0 there
                    bf16x8 B = *(const bf16x8*)&s_h1[pl * 16 + c0];
                    #pragma unroll
                    for (int mt2 = 0; mt2 < 2; mt2++) {
                        bf16x8 A = *(const bf16x8*)(Aw2 + ((ks * 2 + mt2) << 9) + lane * 8);
                        acc2[mt2] = __builtin_amdgcn_mfma_f32_16x16x32_bf16(A, B, acc2[mt2], 0, 0, 0);
                    }
                }
                if (p < 324) {
                    #pragma unroll
                    for (int mt2 = 0; mt2 < 2; mt2++) {
                        unsigned int lo = pk2(fmaxf(acc2[mt2][0], 0.f), fmaxf(acc2[mt2][1], 0.f));
                        unsigned int hi = pk2(fmaxf(acc2[mt2][2], 0.f), fmaxf(acc2[mt2][3], 0.f));
                        *(uint2*)((char*)s_h2 + (p * 40 + mt2 * 16 + (g << 2)) * 2) = (uint2){lo, hi};
                    }
                }
            }
        }
        __syncthreads();

        // conv3: D[tap][px]; A=w3, B=h2 pixels. 9 k-steps (taps) x K=32 ch
        {
            const short* Aw3 = Bp3 + (br * 2 + h) * 27648;
            #pragma unroll
            for (int ks = 0; ks < 9; ks++) {
                const int dy = (ks * 11) >> 5;
                const int dx = ks - dy * 3;
                bf16x8 Bf[2];
                #pragma unroll
                for (int nr = 0; nr < 2; nr++) {
                    int pl = (w * 2 + nr + dy) * 18 + j16 + dx;
                    Bf[nr] = *(const bf16x8*)&s_h2[pl * 40 + (g << 3)];
                }
                #pragma unroll
                for (int mt = 0; mt < 6; mt++) {
                    bf16x8 A = *(const bf16x8*)(Aw3 + ((ks * 6 + mt) << 9) + lane * 8);
                    acc[mt][0] = __builtin_amdgcn_mfma_f32_16x16x32_bf16(A, Bf[0], acc[mt][0], 0, 0, 0);
                    acc[mt][1] = __builtin_amdgcn_mfma_f32_16x16x32_bf16(A, Bf[1], acc[mt][1], 0, 0, 0);
                }
            }
        }
        __syncthreads();
    }

    // ---- phase 5: softmax over 96 taps (24/lane x 4 g-lanes) + 9x9 filter ----
    #pragma unroll
    for (int nr = 0; nr < 2; nr++) {
        const int nrow = w * 2 + nr;
        float mx = -1e30f;
        #pragma unroll
        for (int mt = 0; mt < 6; mt++)
            #pragma unroll
            for (int r = 0; r < 4; r++) mx = fmaxf(mx, acc[mt][nr][r]);
        mx = fmaxf(mx, __shfl_xor(mx, 16));
        mx = fmaxf(mx, __shfl_xor(mx, 32));
        float ssum = 0.f, fsum = 0.f;
        #pragma unroll
        for (int mt = 0; mt < 6; mt++)
            #pragma unroll
            for (int r = 0; r < 4; r++) {
                int tap = mt * 16 + (g << 2) + r;
                float e = __expf(acc[mt][nr][r] - mx);   // pads -> 0
                ssum += e;
                int ti = (tap * 57) >> 9;                // tap/9 for tap<96
                int tj = tap - ti * 9;
                int idx = (nrow + ti) * 24 + j16 + tj;
                fsum += e * b2f(s_srcb[idx > 575 ? 575 : idx]);
            }
        ssum += __shfl_xor(ssum, 16);
        ssum += __shfl_xor(ssum, 32);
        fsum += __shfl_xor(fsum, 16);
        fsum += __shfl_xor(fsum, 32);
        if (g == 0)
            pack[((long)(img * 2 + br) << 16) + ((y0 + nrow) << 8) + x0 + j16] = f2b(fsum / ssum);
    }
}

// c1(2->64)+c2(64->1) fused per tile via fp16 dot2; out0 = s + d
__global__ __launch_bounds__(256) void tail_kernel(
    const bf16* __restrict__ pack,
    const f16x2* __restrict__ c1wp, const float* __restrict__ c1b,
    const f16x2* __restrict__ c2wp, const float* __restrict__ c2b,
    const float* __restrict__ d2, float* __restrict__ out0)
{
    __shared__ f16x2 s_xg[400];            // 20x20 of (x_, g_)
    __shared__ _Float16 s_h[22680];        // [324][70] (64 used)

    const int t = threadIdx.x;
    const int tile = blockIdx.x;
    const int img = blockIdx.y;
    const int y0 = (tile >> 4) << 4, x0 = (tile & 15) << 4;

    for (int idx = t; idx < 400; idx += 256) {
        int hy = idx / 20, hx = idx - hy * 20;
        int gy = y0 - 2 + hy, gx = x0 - 2 + hx;
        float vx = 0.f, vg = 0.f;
        if ((unsigned)gy < 256u && (unsigned)gx < 256u) {
            int o = (gy << 8) + gx;
            vx = b2f(pack[((img * 2 + 0) << 16) + o]);
            vg = b2f(pack[((img * 2 + 1) << 16) + o]);
        }
        s_xg[idx] = (f16x2){(_Float16)vx, (_Float16)vg};
    }
    __syncthreads();

    // produce: c1 (fp16 dot2, 9 per channel)
    for (int p = t; p < 324; p += 256) {
        int hy = p / 18, hx = p - hy * 18;
        int gy = y0 - 1 + hy, gx = x0 - 1 + hx;
        bool in = (unsigned)gy < 256u && (unsigned)gx < 256u;
        f16x2 sw[9];
        #pragma unroll
        for (int dy = 0; dy < 3; dy++)
            #pragma unroll
            for (int dx = 0; dx < 3; dx++)
                sw[dy * 3 + dx] = s_xg[(hy + dy) * 20 + hx + dx];
        for (int c = 0; c < 64; c++) {
            float a = c1b[c];
            const f16x2* wp = c1wp + c * 9;
            #pragma unroll
            for (int q = 0; q < 9; q++) a = dot2h(sw[q], wp[q], a);
            s_h[p * 70 + c] = (_Float16)(in ? fmaxf(a, 0.f) : 0.f);
        }
    }
    __syncthreads();

    // consume: c2 = 9 taps x 32 ch-pairs of dot2
    const int ly = t >> 4, lx = t & 15;
    float sacc = c2b[0];
    #pragma unroll
    for (int t9 = 0; t9 < 9; t9++) {
        int pl = (ly + t9 / 3) * 18 + lx + (t9 % 3);
        const _Float16* rowp = s_h + pl * 70;
        const f16x2* wrow = c2wp + t9 * 32;
        #pragma unroll
        for (int cp = 0; cp < 32; cp++) {
            f16x2 hv = *(const f16x2*)&rowp[2 * cp];
            sacc = dot2h(hv, wrow[cp], sacc);
        }
    }
    long o = (long)img * HW + ((y0 + ly) << 8) + (x0 + lx);
    out0[o] = sacc + d2[o];
}

extern "C" void kernel_launch(void* const* d_in, const int* in_sizes, int n_in,
                              void* d_out, int out_size, void* d_ws, size_t ws_size,
                              hipStream_t stream)
{
    const float* origin   = (const float*)d_in[0];
    const float* residual = (const float*)d_in[1];
    const float* fxw1 = (const float*)d_in[2];  const float* fxb1 = (const float*)d_in[3];
    const float* fxw2 = (const float*)d_in[4];  const float* fxb2 = (const float*)d_in[5];
    const float* fxw3 = (const float*)d_in[6];  const float* fxb3 = (const float*)d_in[7];
    const float* fgw1 = (const float*)d_in[8];  const float* fgb1 = (const float*)d_in[9];
    const float* fgw2 = (const float*)d_in[10]; const float* fgb2 = (const float*)d_in[11];
    const float* fgw3 = (const float*)d_in[12]; const float* fgb3 = (const float*)d_in[13];
    const float* c1w  = (const float*)d_in[14]; const float* c1b  = (const float*)d_in[15];
    const float* c2w  = (const float*)d_in[16]; const float* c2b  = (const float*)d_in[17];

    float* out0 = (float*)d_out;                 // out = s + d
    float* out1 = out0 + (long)NB * HW;          // s (temp: packed bf16 x_/g_)
    float* out2 = out1 + (long)NB * HW;          // d
    bf16*  pack = (bf16*)out1;

    short* Bp2 = (short*)d_ws;                   // 20480 shorts
    short* Bp3 = Bp2 + 20480;                    // 110592 shorts
    f16x2* c1wp = (f16x2*)(Bp3 + 110592);        // 576 pairs
    f16x2* c2wp = c1wp + 576;                    // 288 pairs

    pack_w2<<<80, 256, 0, stream>>>(fxw2, fgw2, Bp2);
    pack_w3<<<432, 256, 0, stream>>>(fxw3, fgw3, Bp3);
    pack_c12<<<4, 256, 0, stream>>>(c1w, c2w, c1wp, c2wp);

    branch_kernel<<<dim3(256, 16), 512, 0, stream>>>(
        origin, residual,
        fxw1, fxb1, fxb2, fxb3,
        fgw1, fgb1, fgb2, fgb3,
        Bp2, Bp3, pack, out2);

    tail_kernel<<<dim3(256, 8), 256, 0, stream>>>(pack, c1wp, c1b, c2wp, c2b, out2, out0);

    s_kernel<<<(NB * HW) / 256, 256, 0, stream>>>(out0, out2, out1);
}